// Round 18
// baseline (51.011 us; speedup 1.0000x reference)
//
#include <hip/hip_runtime.h>
#include <hip/hip_fp16.h>

#define IN_DIM  16384
#define OUT_DIM 16384
#define BATCH   2048
#define TPB     512
#define ITS     (OUT_DIM / (TPB * 4))   // 8 j-iterations (4 columns each)
#define CHK     (IN_DIM / (TPB * 8))    // 4 stage chunks of 8 floats per thread

typedef float f32x4 __attribute__((ext_vector_type(4)));

// Two half2's per output column: ab = (c0, c1), cd = (c2, c3). 8 bytes.
struct h2x2 { __half2 ab, cd; };

// OP_COEFFS from the reference, row-major [16][4]
__device__ __constant__ float OPC[16][4] = {
    {0.f, 0.f, 0.f, 0.f}, {0.f, 0.f, 0.f, 1.f}, {0.f, 1.f, 0.f, -1.f}, {0.f, 1.f, 0.f, 0.f},
    {0.f, 0.f, 1.f, -1.f}, {0.f, 0.f, 1.f, 0.f}, {0.f, 1.f, 1.f, -2.f}, {0.f, 1.f, 1.f, -1.f},
    {1.f, -1.f, -1.f, 1.f}, {1.f, -1.f, -1.f, 2.f}, {1.f, 0.f, -1.f, 0.f}, {1.f, 0.f, -1.f, 1.f},
    {1.f, -1.f, 0.f, 0.f}, {1.f, -1.f, 0.f, 1.f}, {1.f, 0.f, 0.f, -1.f}, {1.f, 0.f, 0.f, 0.f}};

// Prep: coef (f16x4) + packed f16-LDS byte offsets: (idx_a*2) | (idx_b*2)<<16.
__global__ __launch_bounds__(256) void prep_kernel(const float* __restrict__ w,
                                                   const int* __restrict__ ia,
                                                   const int* __restrict__ ib,
                                                   h2x2* __restrict__ coefh,
                                                   unsigned* __restrict__ packed) {
    int j = blockIdx.x * 256 + threadIdx.x;
    if (j >= OUT_DIM) return;

    const float4* wr = (const float4*)(w + (size_t)j * 16);
    float wv[16];
    float4 w0 = wr[0], w1 = wr[1], w2 = wr[2], w3 = wr[3];
    wv[0] = w0.x; wv[1] = w0.y; wv[2] = w0.z; wv[3] = w0.w;
    wv[4] = w1.x; wv[5] = w1.y; wv[6] = w1.z; wv[7] = w1.w;
    wv[8] = w2.x; wv[9] = w2.y; wv[10] = w2.z; wv[11] = w2.w;
    wv[12] = w3.x; wv[13] = w3.y; wv[14] = w3.z; wv[15] = w3.w;

    float m = wv[0];
#pragma unroll
    for (int k = 1; k < 16; ++k) m = fmaxf(m, wv[k]);
    float s = 0.f;
#pragma unroll
    for (int k = 0; k < 16; ++k) { wv[k] = expf(wv[k] - m); s += wv[k]; }
    float inv = 1.f / s;

    float c0 = 0.f, c1 = 0.f, c2 = 0.f, c3 = 0.f;
#pragma unroll
    for (int k = 0; k < 16; ++k) {
        float p = wv[k];
        c0 = fmaf(p, OPC[k][0], c0);
        c1 = fmaf(p, OPC[k][1], c1);
        c2 = fmaf(p, OPC[k][2], c2);
        c3 = fmaf(p, OPC[k][3], c3);
    }
    h2x2 c;
    c.ab = __floats2half2_rn(c0 * inv, c1 * inv);
    c.cd = __floats2half2_rn(c2 * inv, c3 * inv);
    coefh[j] = c;
    packed[j] = ((unsigned)ia[j] << 1) | ((unsigned)ib[j] << 17);
}

__device__ __forceinline__ unsigned pack2(float a, float b) {
    return __builtin_bit_cast(unsigned, __builtin_amdgcn_cvt_pkrtz(a, b));
}

// R17 structure (best: 50.3us) with ONE change: out-stores via inline asm
// `global_store_dwordx4 ... off nt sc1`. R17's builtin NT store helped
// (L2 write-pollution relief) but FETCH_SIZE stayed 66 MB: out still
// ALLOCATES in the 256 MiB L3 and evicts half of x every replay. sc1 raises
// the write scope past the MALL -> out lines stream to HBM without L3
// allocation -> x (+tables) become fully L3-resident -> FETCH ~0 and the
// HBM budget drops 197 -> ~135 MB.
__global__ __launch_bounds__(TPB, 4) void logic_kernel(const float* __restrict__ x,
                                                       const unsigned* __restrict__ packed,
                                                       const h2x2* __restrict__ coefh,
                                                       float* __restrict__ out) {
    __shared__ __half lds[IN_DIM];  // 32 KiB

    const int tid = threadIdx.x;
    const size_t row = blockIdx.x;

    // Stage: 8 float4 loads, pack f32->f16, ds_write.
    {
        const float4* s4 = (const float4*)(x + row * IN_DIM);
        uint4 tt[CHK];
#pragma unroll
        for (int c = 0; c < CHK; ++c) {
            float4 v0 = s4[(c * TPB + tid) * 2 + 0];
            float4 v1 = s4[(c * TPB + tid) * 2 + 1];
            tt[c].x = pack2(v0.x, v0.y); tt[c].y = pack2(v0.z, v0.w);
            tt[c].z = pack2(v1.x, v1.y); tt[c].w = pack2(v1.z, v1.w);
        }
#pragma unroll
        for (int c = 0; c < CHK; ++c)
            *(uint4*)((char*)lds + (size_t)(c * TPB + tid) * 16) = tt[c];
    }

    // Prefetch iteration 0's pi/cf while waiting on the barrier.
    uint4 pi = *(const uint4*)(packed + tid * 4);
    h2x2 cA = coefh[tid * 4 + 0];
    h2x2 cB = coefh[tid * 4 + 1];
    h2x2 cC = coefh[tid * 4 + 2];
    h2x2 cD = coefh[tid * 4 + 3];

    __syncthreads();

    const char* bufc = (const char*)lds;
    float* outr = out + row * IN_DIM;

#pragma unroll
    for (int it = 0; it < ITS; ++it) {
        // Issue next iteration's loads first; they fly under this iteration's
        // gather + FMA + store.
        uint4 pin = pi;
        h2x2 nA = cA, nB = cB, nC = cC, nD = cD;
        if (it + 1 < ITS) {
            const int jn = ((it + 1) * TPB + tid) * 4;
            pin = *(const uint4*)(packed + jn);
            nA = coefh[jn + 0];
            nB = coefh[jn + 1];
            nC = coefh[jn + 2];
            nD = coefh[jn + 3];
        }
        __builtin_amdgcn_sched_barrier(0);  // keep prefetch issue ahead of compute

        const int j0 = (it * TPB + tid) * 4;
        f32x4 o;
#define COL(P, CF, FLD)                                                             \
        {                                                                           \
            float a = __half2float(*(const __half*)(bufc + ((P) & 0xFFFFu)));       \
            float b = __half2float(*(const __half*)(bufc + ((P) >> 16)));           \
            float c0 = __low2float(CF.ab), c1 = __high2float(CF.ab);                \
            float c2 = __low2float(CF.cd), c3 = __high2float(CF.cd);                \
            o.FLD = fmaf(a, fmaf(c3, b, c1), fmaf(c2, b, c0));                      \
        }
        COL(pi.x, cA, x)
        COL(pi.y, cB, y)
        COL(pi.z, cC, z)
        COL(pi.w, cD, w)
#undef COL
        {
            const float* pdst = outr + j0;
            asm volatile("global_store_dwordx4 %0, %1, off nt sc1"
                         :: "v"(pdst), "v"(o)
                         : "memory");
        }

        pi = pin; cA = nA; cB = nB; cC = nC; cD = nD;
    }
}

extern "C" void kernel_launch(void* const* d_in, const int* in_sizes, int n_in,
                              void* d_out, int out_size, void* d_ws, size_t ws_size,
                              hipStream_t stream) {
    const float* x = (const float*)d_in[0];
    const int* ia = (const int*)d_in[1];
    const int* ib = (const int*)d_in[2];
    const float* w = (const float*)d_in[3];
    float* out = (float*)d_out;

    // ws layout: [0, 128 KiB) coefh h2x2[OUT_DIM]; [128 KiB, 192 KiB) packed u32[OUT_DIM]
    h2x2* coefh = (h2x2*)d_ws;
    unsigned* packed = (unsigned*)((char*)d_ws + (size_t)OUT_DIM * sizeof(h2x2));

    prep_kernel<<<OUT_DIM / 256, 256, 0, stream>>>(w, ia, ib, coefh, packed);
    logic_kernel<<<BATCH, TPB, 0, stream>>>(x, packed, coefh, out);
}

// Round 19
// 48.655 us; speedup vs baseline: 1.0484x; 1.0484x over previous
//
#include <hip/hip_runtime.h>
#include <hip/hip_fp16.h>

#define IN_DIM  16384
#define OUT_DIM 16384
#define BATCH   2048
#define TPB     512
#define NBLK    (BATCH / 2)             // 1024 blocks, 2 rows each
#define ITS     (OUT_DIM / (TPB * 4))   // 8 j-iterations (4 columns each)
#define CHK     (IN_DIM / (TPB * 8))    // 4 stage chunks of 8 columns per thread

typedef float f32x4 __attribute__((ext_vector_type(4)));

// Two half2's per output column: ab = (c0, c1), cd = (c2, c3). 8 bytes.
struct h2x2 { __half2 ab, cd; };

// OP_COEFFS from the reference, row-major [16][4]
__device__ __constant__ float OPC[16][4] = {
    {0.f, 0.f, 0.f, 0.f}, {0.f, 0.f, 0.f, 1.f}, {0.f, 1.f, 0.f, -1.f}, {0.f, 1.f, 0.f, 0.f},
    {0.f, 0.f, 1.f, -1.f}, {0.f, 0.f, 1.f, 0.f}, {0.f, 1.f, 1.f, -2.f}, {0.f, 1.f, 1.f, -1.f},
    {1.f, -1.f, -1.f, 1.f}, {1.f, -1.f, -1.f, 2.f}, {1.f, 0.f, -1.f, 0.f}, {1.f, 0.f, -1.f, 1.f},
    {1.f, -1.f, 0.f, 0.f}, {1.f, -1.f, 0.f, 1.f}, {1.f, 0.f, 0.f, -1.f}, {1.f, 0.f, 0.f, 0.f}};

// Prep: coef (f16x4) + packed pair-LDS byte offsets: (idx_a*4) | (idx_b*4)<<16.
__global__ __launch_bounds__(256) void prep_kernel(const float* __restrict__ w,
                                                   const int* __restrict__ ia,
                                                   const int* __restrict__ ib,
                                                   h2x2* __restrict__ coefh,
                                                   unsigned* __restrict__ packed) {
    int j = blockIdx.x * 256 + threadIdx.x;
    if (j >= OUT_DIM) return;

    const float4* wr = (const float4*)(w + (size_t)j * 16);
    float wv[16];
    float4 w0 = wr[0], w1 = wr[1], w2 = wr[2], w3 = wr[3];
    wv[0] = w0.x; wv[1] = w0.y; wv[2] = w0.z; wv[3] = w0.w;
    wv[4] = w1.x; wv[5] = w1.y; wv[6] = w1.z; wv[7] = w1.w;
    wv[8] = w2.x; wv[9] = w2.y; wv[10] = w2.z; wv[11] = w2.w;
    wv[12] = w3.x; wv[13] = w3.y; wv[14] = w3.z; wv[15] = w3.w;

    float m = wv[0];
#pragma unroll
    for (int k = 1; k < 16; ++k) m = fmaxf(m, wv[k]);
    float s = 0.f;
#pragma unroll
    for (int k = 0; k < 16; ++k) { wv[k] = expf(wv[k] - m); s += wv[k]; }
    float inv = 1.f / s;

    float c0 = 0.f, c1 = 0.f, c2 = 0.f, c3 = 0.f;
#pragma unroll
    for (int k = 0; k < 16; ++k) {
        float p = wv[k];
        c0 = fmaf(p, OPC[k][0], c0);
        c1 = fmaf(p, OPC[k][1], c1);
        c2 = fmaf(p, OPC[k][2], c2);
        c3 = fmaf(p, OPC[k][3], c3);
    }
    h2x2 c;
    c.ab = __floats2half2_rn(c0 * inv, c1 * inv);
    c.cd = __floats2half2_rn(c2 * inv, c3 * inv);
    coefh[j] = c;
    packed[j] = ((unsigned)ia[j] << 2) | ((unsigned)ib[j] << 18);
}

__device__ __forceinline__ unsigned pack2(float a, float b) {
    return __builtin_bit_cast(unsigned, __builtin_amdgcn_cvt_pkrtz(a, b));
}

// Pair-row f16 single-shot + NT stores (R17's win + R13's confirmed
// conflict-halving mechanism, now combined): 2 rows interleaved in LDS as
// half2{A[i],B[i]} at byte 4i (64 KiB, 2 blocks/CU). One ds_read_b32 serves
// BOTH rows for one operand -> per-CU LDS gather instrs and bank conflicts
// halve (the largest non-HBM term in the sum-model); 1024 blocks halve
// per-block stage/launch overheads. Depth-1 pi/cf prefetch; NT out-stores
// keep the L2 write-path relief. (512,2) -> 128-VGPR cap for the 16-float4
// stage window; demand ~100 -> no spill.
__global__ __launch_bounds__(TPB, 2) void logic_kernel(const float* __restrict__ x,
                                                       const unsigned* __restrict__ packed,
                                                       const h2x2* __restrict__ coefh,
                                                       float* __restrict__ out) {
    __shared__ __half lds[2 * IN_DIM];  // 64 KiB interleaved pair buffer

    const int tid = threadIdx.x;
    const size_t rowA = (size_t)blockIdx.x * 2;

    // Stage both rows: 16 float4 loads, pack interleaved f16 pairs, 8x16B writes.
    {
        const float4* sA = (const float4*)(x + rowA * IN_DIM);
        const float4* sB = (const float4*)(x + (rowA + 1) * IN_DIM);
#pragma unroll
        for (int c = 0; c < CHK; ++c) {
            const int m = (c * TPB + tid) * 2;
            float4 a0 = sA[m + 0], a1 = sA[m + 1];
            float4 b0 = sB[m + 0], b1 = sB[m + 1];
            uint4 t0, t1;
            t0.x = pack2(a0.x, b0.x); t0.y = pack2(a0.y, b0.y);
            t0.z = pack2(a0.z, b0.z); t0.w = pack2(a0.w, b0.w);
            t1.x = pack2(a1.x, b1.x); t1.y = pack2(a1.y, b1.y);
            t1.z = pack2(a1.z, b1.z); t1.w = pack2(a1.w, b1.w);
            char* dst = (char*)lds + (size_t)(c * TPB + tid) * 32;
            *(uint4*)dst = t0;
            *(uint4*)(dst + 16) = t1;
        }
    }

    // Prefetch iteration 0's pi/cf while waiting on the barrier.
    uint4 pi = *(const uint4*)(packed + tid * 4);
    h2x2 cA = coefh[tid * 4 + 0];
    h2x2 cB = coefh[tid * 4 + 1];
    h2x2 cC = coefh[tid * 4 + 2];
    h2x2 cD = coefh[tid * 4 + 3];

    __syncthreads();

    const char* bufc = (const char*)lds;
    float* outrA = out + rowA * IN_DIM;
    float* outrB = outrA + IN_DIM;

#pragma unroll
    for (int it = 0; it < ITS; ++it) {
        // Next iteration's pi/cf fly under this iteration's gather+FMA+store.
        uint4 pin = pi;
        h2x2 nA = cA, nB = cB, nC = cC, nD = cD;
        if (it + 1 < ITS) {
            const int jn = ((it + 1) * TPB + tid) * 4;
            pin = *(const uint4*)(packed + jn);
            nA = coefh[jn + 0];
            nB = coefh[jn + 1];
            nC = coefh[jn + 2];
            nD = coefh[jn + 3];
        }
        __builtin_amdgcn_sched_barrier(0);  // keep prefetch issue ahead of compute

        const int j0 = (it * TPB + tid) * 4;
        f32x4 oA, oB;
#define COL(P, CF, FLD)                                                              \
        {                                                                            \
            __half2 ap = *(const __half2*)(bufc + ((P) & 0xFFFFu));                  \
            __half2 bp = *(const __half2*)(bufc + ((P) >> 16));                      \
            float aA = __low2float(ap), aB = __high2float(ap);                       \
            float bA = __low2float(bp), bB = __high2float(bp);                       \
            float c0 = __low2float(CF.ab), c1 = __high2float(CF.ab);                 \
            float c2 = __low2float(CF.cd), c3 = __high2float(CF.cd);                 \
            oA.FLD = fmaf(aA, fmaf(c3, bA, c1), fmaf(c2, bA, c0));                   \
            oB.FLD = fmaf(aB, fmaf(c3, bB, c1), fmaf(c2, bB, c0));                   \
        }
        COL(pi.x, cA, x)
        COL(pi.y, cB, y)
        COL(pi.z, cC, z)
        COL(pi.w, cD, w)
#undef COL
        __builtin_nontemporal_store(oA, (f32x4*)(outrA + j0));
        __builtin_nontemporal_store(oB, (f32x4*)(outrB + j0));

        pi = pin; cA = nA; cB = nB; cC = nC; cD = nD;
    }
}

extern "C" void kernel_launch(void* const* d_in, const int* in_sizes, int n_in,
                              void* d_out, int out_size, void* d_ws, size_t ws_size,
                              hipStream_t stream) {
    const float* x = (const float*)d_in[0];
    const int* ia = (const int*)d_in[1];
    const int* ib = (const int*)d_in[2];
    const float* w = (const float*)d_in[3];
    float* out = (float*)d_out;

    // ws layout: [0, 128 KiB) coefh h2x2[OUT_DIM]; [128 KiB, 192 KiB) packed u32[OUT_DIM]
    h2x2* coefh = (h2x2*)d_ws;
    unsigned* packed = (unsigned*)((char*)d_ws + (size_t)OUT_DIM * sizeof(h2x2));

    prep_kernel<<<OUT_DIM / 256, 256, 0, stream>>>(w, ia, ib, coefh, packed);
    logic_kernel<<<NBLK, TPB, 0, stream>>>(x, packed, coefh, out);
}